// Round 2
// baseline (889.051 us; speedup 1.0000x reference)
//
#include <hip/hip_runtime.h>
#include <hip/hip_bf16.h>
#include <hip/hip_fp16.h>

// Problem dims
#define A_DIM 4608   // C*9 patch-feature rows
#define L_DIM 4096   // (H/3)*(W/3) spatial columns
#define CH    512
#define H_DIM 192
#define W_DIM 192

typedef _Float16 half8 __attribute__((ext_vector_type(8)));
typedef float   floatx4 __attribute__((ext_vector_type(4)));

// ---------------------------------------------------------------------------
// Pass 1: unfold(x) -> row-major (A_DIM x L_DIM) f16 hi/lo split + 1/row-norm.
// One block per (c, kh, which-input). Thread reads the 3 consecutive floats of
// a kw-triple (dense, coalesced, each input float read exactly once) and
// scatters to the 3 rows a = c*9 + kh*3 + kw at column l = ph*64 + pw.
// ---------------------------------------------------------------------------
__global__ __launch_bounds__(256) void prep_kernel(
    const float* __restrict__ x0, const float* __restrict__ x1,
    _Float16* __restrict__ Uhi0, _Float16* __restrict__ Ulo0,
    _Float16* __restrict__ Uhi1, _Float16* __restrict__ Ulo1,
    float* __restrict__ nr0, float* __restrict__ nr1) {
  const int which = blockIdx.z;
  const float* __restrict__ x = which ? x1 : x0;
  _Float16* __restrict__ Uhi = which ? Uhi1 : Uhi0;
  _Float16* __restrict__ Ulo = which ? Ulo1 : Ulo0;
  float* __restrict__ nrecip = which ? nr1 : nr0;

  const int c = blockIdx.x, kh = blockIdx.y;
  const int a0 = c * 9 + kh * 3;
  const float* __restrict__ xb = x + (size_t)c * (H_DIM * W_DIM) + kh * W_DIM;
  const int t = threadIdx.x;

  float ss0 = 0.f, ss1 = 0.f, ss2 = 0.f;
#pragma unroll
  for (int it = 0; it < 16; ++it) {
    const int l = it * 256 + t;
    const int ph = l >> 6, pw = l & 63;
    const float* __restrict__ p = xb + (3 * ph) * W_DIM + 3 * pw;
    const float v0 = p[0], v1 = p[1], v2 = p[2];
    ss0 += v0 * v0; ss1 += v1 * v1; ss2 += v2 * v2;
    const _Float16 h0 = (_Float16)v0, h1 = (_Float16)v1, h2 = (_Float16)v2;
    Uhi[(size_t)(a0 + 0) * L_DIM + l] = h0;
    Uhi[(size_t)(a0 + 1) * L_DIM + l] = h1;
    Uhi[(size_t)(a0 + 2) * L_DIM + l] = h2;
    Ulo[(size_t)(a0 + 0) * L_DIM + l] = (_Float16)(v0 - (float)h0);
    Ulo[(size_t)(a0 + 1) * L_DIM + l] = (_Float16)(v1 - (float)h1);
    Ulo[(size_t)(a0 + 2) * L_DIM + l] = (_Float16)(v2 - (float)h2);
  }
  // block reduction of the three sums of squares
  __shared__ float wss[3][4];
  const int wid = t >> 6, lane = t & 63;
  float s[3] = {ss0, ss1, ss2};
#pragma unroll
  for (int kw = 0; kw < 3; ++kw) {
    float v = s[kw];
#pragma unroll
    for (int off = 32; off > 0; off >>= 1) v += __shfl_down(v, off, 64);
    if (lane == 0) wss[kw][wid] = v;
  }
  __syncthreads();
  if (t < 3) {
    const float tot = wss[t][0] + wss[t][1] + wss[t][2] + wss[t][3];
    nrecip[a0 + t] = 1.0f / sqrtf(tot);
  }
}

// ---------------------------------------------------------------------------
// Pass 2: D[i,j] = sty_i . img_j via 3-term f16-split MFMA (hi*hi+hi*lo+lo*hi),
// fused column-wise max/argmax of v = img_nr[i] * D[i,j] into packed atomics.
// LDS layout: seg-major within each 16-row chunk so that fragment ds_read_b128
// is chunk_base + lane*16 (contiguous, conflict-free). GLDS still writes
// lane-contiguous (dest = t*16 B); only the global (row,seg)->lane map changed.
// ---------------------------------------------------------------------------
#define GLDS(g, l)                                                          \
  __builtin_amdgcn_global_load_lds(                                        \
      (const __attribute__((address_space(1))) void*)(g),                   \
      (__attribute__((address_space(3))) void*)(l), 16, 0, 0)

__global__ __launch_bounds__(256) void gemm_max_kernel(
    const _Float16* __restrict__ Shi, const _Float16* __restrict__ Slo,
    const _Float16* __restrict__ Ihi, const _Float16* __restrict__ Ilo,
    const float* __restrict__ img_nr,
    unsigned long long* __restrict__ packed) {
  __shared__ _Float16 sAh[128 * 32];
  __shared__ _Float16 sAl[128 * 32];
  __shared__ _Float16 sBh[128 * 32];
  __shared__ _Float16 sBl[128 * 32];

  const int t = threadIdx.x;
  const int lane = t & 63, wv = t >> 6;
  const int wr = wv >> 1, wc = wv & 1;           // 2x2 waves over 128x128 tile
  const int row0 = blockIdx.y * 128;             // sty rows (i)
  const int col0 = blockIdx.x * 128;             // img rows (j)
  const int quad = lane >> 4;
  const int l15 = lane & 15;

  floatx4 acc[4][4];
#pragma unroll
  for (int rf = 0; rf < 4; ++rf)
#pragma unroll
    for (int cf = 0; cf < 4; ++cf) acc[rf][cf] = (floatx4)0.f;

  // staging map (seg-major chunks): lane L of wave w fetches row w*16+(L&15),
  // k-seg (L>>4); LDS dest = t*16 bytes (lane-contiguous, GLDS-legal).
  const int sr = ((t >> 6) << 4) | (t & 15);
  const int sseg = (t >> 4) & 3;
  const size_t gA = (size_t)(row0 + sr) * L_DIM + sseg * 8;
  const size_t gB = (size_t)(col0 + sr) * L_DIM + sseg * 8;
  const int lofs = t * 8;  // halves == t*16 bytes
  const size_t rskip = (size_t)64 * L_DIM;

  for (int k0 = 0; k0 < L_DIM; k0 += 32) {
    __syncthreads();  // previous compute done before overwrite
    GLDS(Shi + gA + k0,         &sAh[lofs]);
    GLDS(Shi + gA + k0 + rskip, &sAh[lofs + 2048]);
    GLDS(Slo + gA + k0,         &sAl[lofs]);
    GLDS(Slo + gA + k0 + rskip, &sAl[lofs + 2048]);
    GLDS(Ihi + gB + k0,         &sBh[lofs]);
    GLDS(Ihi + gB + k0 + rskip, &sBh[lofs + 2048]);
    GLDS(Ilo + gB + k0,         &sBl[lofs]);
    GLDS(Ilo + gB + k0 + rskip, &sBl[lofs + 2048]);
    __syncthreads();  // loads visible

    half8 ah[4], al[4], bh[4], bl[4];
#pragma unroll
    for (int rf = 0; rf < 4; ++rf) {
      const int off = (wr * 4 + rf) * 512 + lane * 8;  // chunk base + lane*16B
      ah[rf] = *(const half8*)&sAh[off];
      al[rf] = *(const half8*)&sAl[off];
    }
#pragma unroll
    for (int cf = 0; cf < 4; ++cf) {
      const int off = (wc * 4 + cf) * 512 + lane * 8;
      bh[cf] = *(const half8*)&sBh[off];
      bl[cf] = *(const half8*)&sBl[off];
    }
#pragma unroll
    for (int rf = 0; rf < 4; ++rf)
#pragma unroll
      for (int cf = 0; cf < 4; ++cf) {
        acc[rf][cf] = __builtin_amdgcn_mfma_f32_16x16x32_f16(ah[rf], bh[cf], acc[rf][cf], 0, 0, 0);
        acc[rf][cf] = __builtin_amdgcn_mfma_f32_16x16x32_f16(ah[rf], bl[cf], acc[rf][cf], 0, 0, 0);
        acc[rf][cf] = __builtin_amdgcn_mfma_f32_16x16x32_f16(al[rf], bh[cf], acc[rf][cf], 0, 0, 0);
      }
  }

  // Epilogue: v[i,j] = img_nr[i] * D[i,j]; column-wise max+argmax (first-index
  // tie-break). C/D layout: row = quad*4 + reg, col = lane&15.
  float nr[4][4];
#pragma unroll
  for (int rf = 0; rf < 4; ++rf) {
    const int i = row0 + wr * 64 + rf * 16 + quad * 4;
    const floatx4 n4 = *(const floatx4*)&img_nr[i];
#pragma unroll
    for (int r = 0; r < 4; ++r) nr[rf][r] = n4[r];
  }
#pragma unroll
  for (int cf = 0; cf < 4; ++cf) {
    const int j = col0 + wc * 64 + cf * 16 + l15;
    float best = -3.4e38f;
    int bi = 0x7FFFFFFF;
#pragma unroll
    for (int rf = 0; rf < 4; ++rf)
#pragma unroll
      for (int r = 0; r < 4; ++r) {
        const int i = row0 + wr * 64 + rf * 16 + quad * 4 + r;
        const float v = acc[rf][cf][r] * nr[rf][r];
        if (v > best) { best = v; bi = i; }   // ascending i => first-index wins
      }
    // reduce across the 4 quads holding this column
#pragma unroll
    for (int off = 16; off < 64; off <<= 1) {
      const float ov = __shfl_xor(best, off, 64);
      const int oi = __shfl_xor(bi, off, 64);
      if (ov > best || (ov == best && oi < bi)) { best = ov; bi = oi; }
    }
    if (quad == 0) {
      const unsigned u = __float_as_uint(best);
      const unsigned key = (u & 0x80000000u) ? ~u : (u | 0x80000000u);
      const unsigned long long pk =
          ((unsigned long long)key << 32) | (unsigned)(~(unsigned)bi);
      atomicMax(&packed[j], pk);
    }
  }
}

// ---------------------------------------------------------------------------
// Pass 3: decode packed (max over i of img_nr[i]*D[i,j]), apply sty_nr[j],
// write outputs: out[0..A) = nearest (as float), out[A..2A) = max_sim.
// ---------------------------------------------------------------------------
__global__ __launch_bounds__(256) void finalize_kernel(
    const unsigned long long* __restrict__ packed,
    const float* __restrict__ sty_nr, float* __restrict__ out) {
  const int j = blockIdx.x * 256 + threadIdx.x;
  if (j >= A_DIM) return;
  const unsigned long long p = packed[j];
  const unsigned key = (unsigned)(p >> 32);
  const unsigned u = (key & 0x80000000u) ? (key ^ 0x80000000u) : ~key;
  const float v = __uint_as_float(u);
  const int idx = (int)(~(unsigned)(p & 0xFFFFFFFFu));
  out[j] = (float)idx;
  out[A_DIM + j] = v * sty_nr[j];
}

extern "C" void kernel_launch(void* const* d_in, const int* in_sizes, int n_in,
                              void* d_out, int out_size, void* d_ws, size_t ws_size,
                              hipStream_t stream) {
  const float* model = (const float*)d_in[0];  // img side
  const float* style = (const float*)d_in[1];  // sty side
  float* out = (float*)d_out;
  char* ws = (char*)d_ws;

  const size_t usz = (size_t)A_DIM * L_DIM * 2;  // one f16 matrix: 37,748,736 B
  _Float16* img_hi = (_Float16*)(ws);
  _Float16* img_lo = (_Float16*)(ws + usz);
  _Float16* sty_hi = (_Float16*)(ws + 2 * usz);
  _Float16* sty_lo = (_Float16*)(ws + 3 * usz);
  float* img_nr = (float*)(ws + 4 * usz);
  float* sty_nr = img_nr + A_DIM;
  unsigned long long* packed = (unsigned long long*)(img_nr + 2 * A_DIM);

  hipMemsetAsync(packed, 0, (size_t)A_DIM * 8, stream);
  prep_kernel<<<dim3(CH, 3, 2), 256, 0, stream>>>(
      model, style, img_hi, img_lo, sty_hi, sty_lo, img_nr, sty_nr);
  gemm_max_kernel<<<dim3(36, 36), 256, 0, stream>>>(sty_hi, sty_lo, img_hi,
                                                    img_lo, img_nr, packed);
  finalize_kernel<<<18, 256, 0, stream>>>(packed, sty_nr, out);
}

// Round 3
// 766.748 us; speedup vs baseline: 1.1595x; 1.1595x over previous
//
#include <hip/hip_runtime.h>
#include <hip/hip_bf16.h>
#include <hip/hip_fp16.h>

// Problem dims
#define A_DIM 4608   // C*9 patch-feature rows
#define L_DIM 4096   // (H/3)*(W/3) spatial columns
#define CH    512
#define H_DIM 192
#define W_DIM 192

typedef _Float16 half8 __attribute__((ext_vector_type(8)));
typedef float   floatx4 __attribute__((ext_vector_type(4)));
typedef float   floatx16 __attribute__((ext_vector_type(16)));

// ---------------------------------------------------------------------------
// Pass 1: unfold(x) -> row-major (A_DIM x L_DIM) f16 hi/lo split + 1/row-norm.
// One block per (c, kh, which-input); dense coalesced reads of kw-triples.
// ---------------------------------------------------------------------------
__global__ __launch_bounds__(256) void prep_kernel(
    const float* __restrict__ x0, const float* __restrict__ x1,
    _Float16* __restrict__ Uhi0, _Float16* __restrict__ Ulo0,
    _Float16* __restrict__ Uhi1, _Float16* __restrict__ Ulo1,
    float* __restrict__ nr0, float* __restrict__ nr1) {
  const int which = blockIdx.z;
  const float* __restrict__ x = which ? x1 : x0;
  _Float16* __restrict__ Uhi = which ? Uhi1 : Uhi0;
  _Float16* __restrict__ Ulo = which ? Ulo1 : Ulo0;
  float* __restrict__ nrecip = which ? nr1 : nr0;

  const int c = blockIdx.x, kh = blockIdx.y;
  const int a0 = c * 9 + kh * 3;
  const float* __restrict__ xb = x + (size_t)c * (H_DIM * W_DIM) + kh * W_DIM;
  const int t = threadIdx.x;

  float ss0 = 0.f, ss1 = 0.f, ss2 = 0.f;
#pragma unroll
  for (int it = 0; it < 16; ++it) {
    const int l = it * 256 + t;
    const int ph = l >> 6, pw = l & 63;
    const float* __restrict__ p = xb + (3 * ph) * W_DIM + 3 * pw;
    const float v0 = p[0], v1 = p[1], v2 = p[2];
    ss0 += v0 * v0; ss1 += v1 * v1; ss2 += v2 * v2;
    const _Float16 h0 = (_Float16)v0, h1 = (_Float16)v1, h2 = (_Float16)v2;
    Uhi[(size_t)(a0 + 0) * L_DIM + l] = h0;
    Uhi[(size_t)(a0 + 1) * L_DIM + l] = h1;
    Uhi[(size_t)(a0 + 2) * L_DIM + l] = h2;
    Ulo[(size_t)(a0 + 0) * L_DIM + l] = (_Float16)(v0 - (float)h0);
    Ulo[(size_t)(a0 + 1) * L_DIM + l] = (_Float16)(v1 - (float)h1);
    Ulo[(size_t)(a0 + 2) * L_DIM + l] = (_Float16)(v2 - (float)h2);
  }
  __shared__ float wss[3][4];
  const int wid = t >> 6, lane = t & 63;
  float s[3] = {ss0, ss1, ss2};
#pragma unroll
  for (int kw = 0; kw < 3; ++kw) {
    float v = s[kw];
#pragma unroll
    for (int off = 32; off > 0; off >>= 1) v += __shfl_down(v, off, 64);
    if (lane == 0) wss[kw][wid] = v;
  }
  __syncthreads();
  if (t < 3) {
    const float tot = wss[t][0] + wss[t][1] + wss[t][2] + wss[t][3];
    nrecip[a0 + t] = 1.0f / sqrtf(tot);
  }
}

// ---------------------------------------------------------------------------
// Pass 2: D[i,j] = sty_i . img_j via 3-term f16-split MFMA (hi*hi+hi*lo+lo*hi)
// with the 32x32x16 shape, fused column max/argmax into packed atomics.
//
// LDS layout (per 128x32 buffer, 16B chunks): phys_chunk(row, seg) =
//   row*4 + (seg ^ ((row>>1)&3))
// Writer (GLDS): lane t -> LDS chunk t (dest = t*16B, GLDS-legal), so it
// fetches global row t>>2, seg (t&3)^((t>>3)&3): each 4-lane group still
// covers one contiguous 64B row-chunk -> coalescing identical to round-0.
// Reader: start bank-quad (row&1)*16+(seg^((row>>1)&3))*4 spreads each
// 16-lane group across all 8 bank-quads (2 lanes each = conflict-free).
// ---------------------------------------------------------------------------
#define GLDS(g, l)                                                          \
  __builtin_amdgcn_global_load_lds(                                        \
      (const __attribute__((address_space(1))) void*)(g),                   \
      (__attribute__((address_space(3))) void*)(l), 16, 0, 0)

__global__ __launch_bounds__(256) void gemm_max_kernel(
    const _Float16* __restrict__ Shi, const _Float16* __restrict__ Slo,
    const _Float16* __restrict__ Ihi, const _Float16* __restrict__ Ilo,
    const float* __restrict__ img_nr,
    unsigned long long* __restrict__ packed) {
  __shared__ _Float16 sAh[128 * 32];
  __shared__ _Float16 sAl[128 * 32];
  __shared__ _Float16 sBh[128 * 32];
  __shared__ _Float16 sBl[128 * 32];

  const int t = threadIdx.x;
  const int lane = t & 63, wv = t >> 6;
  const int wr = wv >> 1, wc = wv & 1;           // 2x2 waves over 128x128 tile
  const int row0 = blockIdx.y * 128;             // sty rows (i)
  const int col0 = blockIdx.x * 128;             // img rows (j)
  const int l31 = lane & 31, hs = lane >> 5;

  floatx16 acc[2][2];
#pragma unroll
  for (int rf = 0; rf < 2; ++rf)
#pragma unroll
    for (int cf = 0; cf < 2; ++cf) acc[rf][cf] = (floatx16)0.f;

  // Staging map: lane t -> row t>>2, seg (t&3)^((t>>3)&3); LDS dest t*16B.
  const int sr = t >> 2;
  const int sseg = (t & 3) ^ ((t >> 3) & 3);
  const size_t rskip = (size_t)64 * L_DIM;
  const _Float16* pAh = Shi + (size_t)(row0 + sr) * L_DIM + sseg * 8;
  const _Float16* pAl = Slo + (size_t)(row0 + sr) * L_DIM + sseg * 8;
  const _Float16* pBh = Ihi + (size_t)(col0 + sr) * L_DIM + sseg * 8;
  const _Float16* pBl = Ilo + (size_t)(col0 + sr) * L_DIM + sseg * 8;
  const int lofs = t * 8;  // halves == t*16 bytes

  // Loop-invariant fragment offsets (halves). A-frag for 32x32x16:
  // m = lane&31, k-chunk = kk*2 + (lane>>5); swizzled chunk addressing.
  int aoff[2][2], boff[2][2];
#pragma unroll
  for (int rf = 0; rf < 2; ++rf)
#pragma unroll
    for (int kk = 0; kk < 2; ++kk) {
      const int ar = wr * 64 + rf * 32 + l31;
      const int as = kk * 2 + hs;
      aoff[rf][kk] = (ar * 4 + (as ^ ((ar >> 1) & 3))) * 8;
      const int br = wc * 64 + rf * 32 + l31;
      boff[rf][kk] = (br * 4 + (as ^ ((br >> 1) & 3))) * 8;
    }

  for (int k0 = 0; k0 < L_DIM; k0 += 32) {
    __syncthreads();  // previous compute done before overwrite
    GLDS(pAh,         &sAh[lofs]);
    GLDS(pAh + rskip, &sAh[lofs + 2048]);
    GLDS(pAl,         &sAl[lofs]);
    GLDS(pAl + rskip, &sAl[lofs + 2048]);
    GLDS(pBh,         &sBh[lofs]);
    GLDS(pBh + rskip, &sBh[lofs + 2048]);
    GLDS(pBl,         &sBl[lofs]);
    GLDS(pBl + rskip, &sBl[lofs + 2048]);
    pAh += 32; pAl += 32; pBh += 32; pBl += 32;
    __syncthreads();  // loads visible

    half8 ah[2][2], al[2][2], bh[2][2], bl[2][2];
#pragma unroll
    for (int rf = 0; rf < 2; ++rf)
#pragma unroll
      for (int kk = 0; kk < 2; ++kk) {
        ah[rf][kk] = *(const half8*)&sAh[aoff[rf][kk]];
        al[rf][kk] = *(const half8*)&sAl[aoff[rf][kk]];
        bh[rf][kk] = *(const half8*)&sBh[boff[rf][kk]];
        bl[rf][kk] = *(const half8*)&sBl[boff[rf][kk]];
      }
#pragma unroll
    for (int rf = 0; rf < 2; ++rf)
#pragma unroll
      for (int cf = 0; cf < 2; ++cf)
#pragma unroll
        for (int kk = 0; kk < 2; ++kk) {
          acc[rf][cf] = __builtin_amdgcn_mfma_f32_32x32x16_f16(
              ah[rf][kk], bh[cf][kk], acc[rf][cf], 0, 0, 0);
          acc[rf][cf] = __builtin_amdgcn_mfma_f32_32x32x16_f16(
              ah[rf][kk], bl[cf][kk], acc[rf][cf], 0, 0, 0);
          acc[rf][cf] = __builtin_amdgcn_mfma_f32_32x32x16_f16(
              al[rf][kk], bh[cf][kk], acc[rf][cf], 0, 0, 0);
        }
  }

  // Epilogue: v[i,j] = img_nr[i]*D[i,j]; column max+argmax (first-index wins).
  // 32x32 C/D layout: col = lane&31, row = (reg&3) + 8*(reg>>2) + 4*(lane>>5).
#pragma unroll
  for (int cf = 0; cf < 2; ++cf) {
    const int j = col0 + wc * 64 + cf * 32 + l31;
    float best = -3.4e38f;
    int bi = 0x7FFFFFFF;
#pragma unroll
    for (int rf = 0; rf < 2; ++rf) {
      const int base_i = row0 + wr * 64 + rf * 32 + 4 * hs;
#pragma unroll
      for (int g = 0; g < 4; ++g) {
        const floatx4 n4 = *(const floatx4*)&img_nr[base_i + 8 * g];
#pragma unroll
        for (int r = 0; r < 4; ++r) {
          const int i = base_i + 8 * g + r;
          const float v = acc[rf][cf][g * 4 + r] * n4[r];
          if (v > best) { best = v; bi = i; }  // ascending i => first wins
        }
      }
    }
    // combine the two half-wave row sets (lane ^ 32 holds the same column)
    const float ov = __shfl_xor(best, 32, 64);
    const int oi = __shfl_xor(bi, 32, 64);
    if (ov > best || (ov == best && oi < bi)) { best = ov; bi = oi; }
    if (hs == 0) {
      const unsigned u = __float_as_uint(best);
      const unsigned key = (u & 0x80000000u) ? ~u : (u | 0x80000000u);
      const unsigned long long pk =
          ((unsigned long long)key << 32) | (unsigned)(~(unsigned)bi);
      atomicMax(&packed[j], pk);
    }
  }
}

// ---------------------------------------------------------------------------
// Pass 3: decode packed, apply sty_nr[j]; out[0..A)=nearest, out[A..2A)=max.
// ---------------------------------------------------------------------------
__global__ __launch_bounds__(256) void finalize_kernel(
    const unsigned long long* __restrict__ packed,
    const float* __restrict__ sty_nr, float* __restrict__ out) {
  const int j = blockIdx.x * 256 + threadIdx.x;
  if (j >= A_DIM) return;
  const unsigned long long p = packed[j];
  const unsigned key = (unsigned)(p >> 32);
  const unsigned u = (key & 0x80000000u) ? (key ^ 0x80000000u) : ~key;
  const float v = __uint_as_float(u);
  const int idx = (int)(~(unsigned)(p & 0xFFFFFFFFu));
  out[j] = (float)idx;
  out[A_DIM + j] = v * sty_nr[j];
}

extern "C" void kernel_launch(void* const* d_in, const int* in_sizes, int n_in,
                              void* d_out, int out_size, void* d_ws, size_t ws_size,
                              hipStream_t stream) {
  const float* model = (const float*)d_in[0];  // img side
  const float* style = (const float*)d_in[1];  // sty side
  float* out = (float*)d_out;
  char* ws = (char*)d_ws;

  const size_t usz = (size_t)A_DIM * L_DIM * 2;  // one f16 matrix: 37,748,736 B
  _Float16* img_hi = (_Float16*)(ws);
  _Float16* img_lo = (_Float16*)(ws + usz);
  _Float16* sty_hi = (_Float16*)(ws + 2 * usz);
  _Float16* sty_lo = (_Float16*)(ws + 3 * usz);
  float* img_nr = (float*)(ws + 4 * usz);
  float* sty_nr = img_nr + A_DIM;
  unsigned long long* packed = (unsigned long long*)(img_nr + 2 * A_DIM);

  hipMemsetAsync(packed, 0, (size_t)A_DIM * 8, stream);
  prep_kernel<<<dim3(CH, 3, 2), 256, 0, stream>>>(
      model, style, img_hi, img_lo, sty_hi, sty_lo, img_nr, sty_nr);
  gemm_max_kernel<<<dim3(36, 36), 256, 0, stream>>>(sty_hi, sty_lo, img_hi,
                                                    img_lo, img_nr, packed);
  finalize_kernel<<<18, 256, 0, stream>>>(packed, sty_nr, out);
}